// Round 7
// baseline (335.968 us; speedup 1.0000x reference)
//
#include <hip/hip_runtime.h>

#define NN 2048
#define TT 64
#define FF 16
#define HH 64
#define LL 16
#define TOPKK 10
#define CAP 960

#define AS 72      // Asp row stride in shorts (144 B)
#define XAS 40     // xa row stride in shorts (80 B)
#define XPS 196    // xp row stride in floats

typedef __bf16 bf16x8 __attribute__((ext_vector_type(8)));
typedef float floatx4 __attribute__((ext_vector_type(4)));

union FragCast { uint4 u; bf16x8 b; unsigned short s[8]; };
union Pack4 { unsigned short s[4]; uint2 u; };

__device__ __forceinline__ unsigned short f2bf(float f) {
    unsigned u = __float_as_uint(f);
    return (unsigned short)((u + 0x7fff + ((u >> 16) & 1)) >> 16);
}
__device__ __forceinline__ float bf2f(unsigned short h) {
    return __uint_as_float(((unsigned)h) << 16);
}
__device__ __forceinline__ void split3(float v, unsigned short& a, unsigned short& b, unsigned short& c) {
    a = f2bf(v); float r = v - bf2f(a);
    b = f2bf(r); float r2 = r - bf2f(b);
    c = f2bf(r2);
}
__device__ __forceinline__ float fsigmoid(float x) {
    return __builtin_amdgcn_rcpf(1.f + __builtin_amdgcn_exp2f(-1.442695041f * x));
}
__device__ __forceinline__ float ftanh(float x) {
    return 1.f - 2.f * __builtin_amdgcn_rcpf(1.f + __builtin_amdgcn_exp2f(2.885390082f * x));
}
__device__ __forceinline__ void async_copy16(const void* g, void* l) {
    __builtin_amdgcn_global_load_lds(
        (const __attribute__((address_space(1))) unsigned int*)g,
        (__attribute__((address_space(3))) unsigned int*)l, 16, 0, 0);
}
#define MFMA16(A, B, C) __builtin_amdgcn_mfma_f32_16x16x32_bf16((A), (B), (C), 0, 0, 0)
#define LIMB6(ACC, A1, A2, A3, W)            \
    ACC = MFMA16((A1), (W)[0], ACC);         \
    ACC = MFMA16((A1), (W)[1], ACC);         \
    ACC = MFMA16((A2), (W)[0], ACC);         \
    ACC = MFMA16((A1), (W)[2], ACC);         \
    ACC = MFMA16((A2), (W)[1], ACC);         \
    ACC = MFMA16((A3), (W)[0], ACC);

// ---------------------------------------------------------------------------
// Kernel 1: MFMA GRU v3 (unchanged from R6 except: zeroes cnt, replacing the
// hipMemsetAsync dispatch). 512 blocks x 256 threads, 4 samples/block.
// ---------------------------------------------------------------------------
__global__ __launch_bounds__(256, 2) void gru_kernel(
    const float* __restrict__ x,      // (N,T,F)
    const float* __restrict__ W_ih,   // (192,16)
    const float* __restrict__ W_hh,   // (192,64)
    const float* __restrict__ b_ih,   // (192,)
    const float* __restrict__ b_hh,   // (192,)
    float* __restrict__ h_tail,       // (N,16,64)
    int* __restrict__ cnt)            // (2048,) zeroed here
{
    __shared__ __attribute__((aligned(16))) unsigned short Asp[2][3][16 * AS];
    __shared__ __attribute__((aligned(16))) unsigned short xa[3][16 * XAS];
    __shared__ __attribute__((aligned(16))) float xp[16 * XPS];
    __shared__ __attribute__((aligned(16))) float x_lds[4 * TT * FF];

    const int t    = threadIdx.x;
    const int wv   = t >> 6;
    const int lane = t & 63;
    const int nh   = lane & 15;
    const int quad = lane >> 4;
    const int n0   = blockIdx.x * 4;

    if (t < 4) cnt[blockIdx.x * 4 + t] = 0;

    {
        const char* src = (const char*)(x + (size_t)n0 * TT * FF);
        char* dst = (char*)x_lds;
#pragma unroll
        for (int i = 0; i < 4; ++i)
            async_copy16(src + i * 4096 + t * 16, dst + i * 4096 + t * 16);
    }
    {
        unsigned* p = (unsigned*)&Asp[0][0][0];
        for (int i = t; i < 2 * 3 * 16 * AS / 2; i += 256) p[i] = 0;
        unsigned* q = (unsigned*)&xa[0][0];
        for (int i = t; i < 3 * 16 * XAS / 2; i += 256) q[i] = 0;
    }

    const int jb = wv * 16 + nh;
    const float brz = b_ih[jb] + b_hh[jb];
    const float bz  = b_ih[64 + jb] + b_hh[64 + jb];
    const float bxn = b_ih[128 + jb];
    const float bhn = b_hh[128 + jb];

    bf16x8 wf[3][2][3];
#pragma unroll
    for (int nt = 0; nt < 3; ++nt) {
        const int gr = (wv + 4 * nt) * 16 + nh;
#pragma unroll
        for (int kc = 0; kc < 2; ++kc) {
            const float* p = W_hh + gr * 64 + kc * 32 + quad * 8;
            FragCast f1, f2, f3;
#pragma unroll
            for (int i = 0; i < 8; ++i) split3(p[i], f1.s[i], f2.s[i], f3.s[i]);
            wf[nt][kc][0] = f1.b; wf[nt][kc][1] = f2.b; wf[nt][kc][2] = f3.b;
        }
    }
    bf16x8 wfi[3][3];
#pragma unroll
    for (int nt = 0; nt < 3; ++nt) {
        const int gr = (wv + 4 * nt) * 16 + nh;
        FragCast f1, f2, f3;
#pragma unroll
        for (int i = 0; i < 8; ++i) {
            const float v = (quad < 2) ? W_ih[gr * 16 + quad * 8 + i] : 0.f;
            split3(v, f1.s[i], f2.s[i], f3.s[i]);
        }
        wfi[nt][0] = f1.b; wfi[nt][1] = f2.b; wfi[nt][2] = f3.b;
    }

    __syncthreads();

    float hprev = 0.f;

    for (int chunk = 0; chunk < 16; ++chunk) {
        {
            const int row = t >> 4, f = t & 15;
            const int p = row & 3, sl = row >> 2;
            const float xv = x_lds[p * (TT * FF) + (chunk * 4 + sl) * FF + f];
            unsigned short a, b, c; split3(xv, a, b, c);
            xa[0][row * XAS + f] = a;
            xa[1][row * XAS + f] = b;
            xa[2][row * XAS + f] = c;
        }
        __syncthreads();
        {
            floatx4 xacc0 = {0.f,0.f,0.f,0.f}, xacc1 = {0.f,0.f,0.f,0.f}, xacc2 = {0.f,0.f,0.f,0.f};
            const int aoff = nh * XAS + quad * 8;
            FragCast a1, a2, a3;
            a1.u = *(const uint4*)&xa[0][aoff];
            a2.u = *(const uint4*)&xa[1][aoff];
            a3.u = *(const uint4*)&xa[2][aoff];
            LIMB6(xacc0, a1.b, a2.b, a3.b, wfi[0]);
            LIMB6(xacc1, a1.b, a2.b, a3.b, wfi[1]);
            LIMB6(xacc2, a1.b, a2.b, a3.b, wfi[2]);
#pragma unroll
            for (int r = 0; r < 4; ++r) {
                const int m = quad * 4 + r;
                xp[m * XPS + (wv + 0) * 16 + nh] = xacc0[r];
                xp[m * XPS + (wv + 4) * 16 + nh] = xacc1[r];
                xp[m * XPS + (wv + 8) * 16 + nh] = xacc2[r];
            }
        }
        __syncthreads();

#pragma unroll
        for (int si = 0; si < 4; ++si) {
            const int step = chunk * 4 + si;
            const int rb = step & 1, wb = rb ^ 1;
            floatx4 acc0 = {0.f,0.f,0.f,0.f}, acc1 = {0.f,0.f,0.f,0.f}, acc2 = {0.f,0.f,0.f,0.f};
#pragma unroll
            for (int kc = 0; kc < 2; ++kc) {
                const int aoff = nh * AS + kc * 32 + quad * 8;
                FragCast a1, a2, a3;
                a1.u = *(const uint4*)&Asp[rb][0][aoff];
                a2.u = *(const uint4*)&Asp[rb][1][aoff];
                a3.u = *(const uint4*)&Asp[rb][2][aoff];
                LIMB6(acc0, a1.b, a2.b, a3.b, wf[0][kc]);
                LIMB6(acc1, a1.b, a2.b, a3.b, wf[1][kc]);
                LIMB6(acc2, a1.b, a2.b, a3.b, wf[2][kc]);
            }
            {
                const int xrow = si * 4 + quad;
                const float xr = xp[xrow * XPS + jb];
                const float xz = xp[xrow * XPS + 64 + jb];
                const float xn = xp[xrow * XPS + 128 + jb];
                const float rg = fsigmoid(acc0[0] + xr + brz);
                const float zg = fsigmoid(acc1[0] + xz + bz);
                const float ng = ftanh((xn + bxn) + rg * (acc2[0] + bhn));
                const float h  = (1.f - zg) * ng + zg * hprev;
                hprev = h;
                unsigned short la, lb2, lc; split3(h, la, lb2, lc);
                const int ho = (4 * quad) * AS + jb;
                Asp[wb][0][ho] = la;
                Asp[wb][1][ho] = lb2;
                Asp[wb][2][ho] = lc;
                if (step >= TT - LL)
                    h_tail[((size_t)(n0 + quad) * LL + (step - (TT - LL))) * HH + jb] = h;
            }
            __syncthreads();
        }
    }
}

// ---------------------------------------------------------------------------
// Kernel 2: prep v3 — NO LDS. 512 blocks x 256 threads, 4 samples/block.
// All reads through global/L1: W reads are 16-lane same-address broadcasts
// (Wk+Wq = 8 KB, L1-resident); h rows are shared across the 16 lanes of a
// column group. 4x4 register tile per thread, fully coalesced stores.
// ---------------------------------------------------------------------------
__global__ __launch_bounds__(256, 4) void prep_kernel(
    const float* __restrict__ h_tail, // (N,16,64)
    const float* __restrict__ Wk,     // (64,64)
    const float* __restrict__ Wq,     // (64,64)
    float* __restrict__ Kmat,         // (32768,64) fp32
    unsigned short* __restrict__ Kh,  // (32768,64) bf16
    float* __restrict__ Qf,           // (2048,64) fp32
    unsigned short* __restrict__ Qh)  // (2048,64) bf16
{
    const int t  = threadIdx.x;
    const int rg = t >> 4;            // row group 0..15 (rows rg*4..+3 of 64)
    const int cg = t & 15;            // col group 0..15 (cols cg*4..+3)
    const size_t rbase = (size_t)blockIdx.x * 64;   // 4 samples * 16 lags

    float acc[4][4];
#pragma unroll
    for (int r = 0; r < 4; ++r)
#pragma unroll
        for (int c = 0; c < 4; ++c) acc[r][c] = 0.f;

#pragma unroll
    for (int ci = 0; ci < 16; ++ci) {
        float4 hv[4], wv[4];
#pragma unroll
        for (int r = 0; r < 4; ++r)
            hv[r] = *(const float4*)(h_tail + (rbase + rg * 4 + r) * 64 + ci * 4);
#pragma unroll
        for (int c = 0; c < 4; ++c)
            wv[c] = *(const float4*)(Wk + (cg * 4 + c) * 64 + ci * 4);
#pragma unroll
        for (int r = 0; r < 4; ++r)
#pragma unroll
            for (int c = 0; c < 4; ++c)
                acc[r][c] += hv[r].x * wv[c].x + hv[r].y * wv[c].y
                           + hv[r].z * wv[c].z + hv[r].w * wv[c].w;
    }
#pragma unroll
    for (int r = 0; r < 4; ++r) {
        const size_t row = rbase + rg * 4 + r;
        float4 o; o.x = acc[r][0]; o.y = acc[r][1]; o.z = acc[r][2]; o.w = acc[r][3];
        *(float4*)(Kmat + row * 64 + cg * 4) = o;
        Pack4 p;
#pragma unroll
        for (int c = 0; c < 4; ++c) p.s[c] = f2bf(acc[r][c]);
        *(uint2*)(Kh + row * 64 + cg * 4) = p.u;
    }

    // Q rows: 4 samples x 64 cols = 256 outputs, one per thread
    {
        const int s = t >> 6, j = t & 63;
        const float* hr = h_tail + ((size_t)(blockIdx.x * 4 + s) * LL + 15) * HH;
        const float* wr = Wq + j * 64;
        float a0 = 0.f, a1 = 0.f, a2 = 0.f, a3 = 0.f;
#pragma unroll
        for (int ci = 0; ci < 16; ++ci) {
            const float4 h4 = *(const float4*)(hr + ci * 4);
            const float4 w4 = *(const float4*)(wr + ci * 4);
            a0 += h4.x * w4.x; a1 += h4.y * w4.y; a2 += h4.z * w4.z; a3 += h4.w * w4.w;
        }
        const float a = (a0 + a1) + (a2 + a3);
        const size_t qi = (size_t)(blockIdx.x * 4 + s) * 64 + j;
        Qf[qi] = a;
        Qh[qi] = f2bf(a);
    }
}

// ---------------------------------------------------------------------------
// Kernel 3: MFMA scores + threshold filter, Qtile=64 (unchanged from R6 —
// controlled variable; its true cost surfaces in this round's top-5).
// ---------------------------------------------------------------------------
__global__ __launch_bounds__(512, 4) void score_kernel(
    const unsigned short* __restrict__ Kh,  // (32768,64) bf16
    const unsigned short* __restrict__ Qh,  // (2048,64) bf16
    int* __restrict__ cnt,                  // (2048,)
    int* __restrict__ ids)                  // (2048, CAP)
{
    __shared__ float stat_s[8][4][16];
    __shared__ float stat_q[8][4][16];
    __shared__ float th_s[64];

    const int t    = threadIdx.x;
    const int wave = t >> 6;
    const int lane = t & 63;
    const int n    = lane & 15;
    const int quad = lane >> 4;

    const int qgroup = blockIdx.x >> 4;
    const int split  = blockIdx.x & 15;
    const int tile0  = split * 128 + wave * 16;

    FragCast bq[4][2];
#pragma unroll
    for (int qs = 0; qs < 4; ++qs) {
        const int qg = qgroup * 64 + qs * 16 + n;
        bq[qs][0].u = *(const uint4*)(Qh + (size_t)qg * 64 + quad * 8);
        bq[qs][1].u = *(const uint4*)(Qh + (size_t)qg * 64 + 32 + quad * 8);
    }

    float ssum[4] = {0.f,0.f,0.f,0.f}, ssq[4] = {0.f,0.f,0.f,0.f};
    for (int i = 0; i < 8; ++i) {
        const unsigned short* r = Kh + (size_t)((tile0 + i) * 16 + n) * 64;
        FragCast a0, a1;
        a0.u = *(const uint4*)(r + quad * 8);
        a1.u = *(const uint4*)(r + 32 + quad * 8);
#pragma unroll
        for (int qs = 0; qs < 4; ++qs) {
            floatx4 acc = {0.f, 0.f, 0.f, 0.f};
            acc = MFMA16(a0.b, bq[qs][0].b, acc);
            acc = MFMA16(a1.b, bq[qs][1].b, acc);
#pragma unroll
            for (int j = 0; j < 4; ++j) { ssum[qs] += acc[j]; ssq[qs] += acc[j] * acc[j]; }
        }
    }
#pragma unroll
    for (int qs = 0; qs < 4; ++qs) {
        ssum[qs] += __shfl_xor(ssum[qs], 16, 64); ssq[qs] += __shfl_xor(ssq[qs], 16, 64);
        ssum[qs] += __shfl_xor(ssum[qs], 32, 64); ssq[qs] += __shfl_xor(ssq[qs], 32, 64);
    }
    if (lane < 16) {
#pragma unroll
        for (int qs = 0; qs < 4; ++qs) { stat_s[wave][qs][n] = ssum[qs]; stat_q[wave][qs][n] = ssq[qs]; }
    }
    __syncthreads();
    if (t < 64) {
        const int qs = t >> 4, c = t & 15;
        float S = 0.f, S2 = 0.f;
#pragma unroll
        for (int w = 0; w < 8; ++w) { S += stat_s[w][qs][c]; S2 += stat_q[w][qs][c]; }
        const float inv = 1.f / 1024.f;
        const float mu = S * inv;
        float var = S2 * inv - mu * mu;
        var = var > 0.f ? var : 0.f;
        th_s[t] = mu + 2.6f * __fsqrt_rn(var);
    }
    __syncthreads();
    float th[4];
#pragma unroll
    for (int qs = 0; qs < 4; ++qs) th[qs] = th_s[qs * 16 + n];

    int bufp[16];
    int bcnt = 0;
    {
        FragCast a0, a1, na0, na1;
        const unsigned short* r0 = Kh + (size_t)(tile0 * 16 + n) * 64;
        a0.u = *(const uint4*)(r0 + quad * 8);
        a1.u = *(const uint4*)(r0 + 32 + quad * 8);
        for (int i = 0; i < 16; ++i) {
            if (i + 1 < 16) {
                const unsigned short* r = Kh + (size_t)((tile0 + i + 1) * 16 + n) * 64;
                na0.u = *(const uint4*)(r + quad * 8);
                na1.u = *(const uint4*)(r + 32 + quad * 8);
            }
            const int rowb = (tile0 + i) * 16 + quad * 4;
#pragma unroll
            for (int qs = 0; qs < 4; ++qs) {
                floatx4 acc = {0.f, 0.f, 0.f, 0.f};
                acc = MFMA16(a0.b, bq[qs][0].b, acc);
                acc = MFMA16(a1.b, bq[qs][1].b, acc);
                const int qg = qgroup * 64 + qs * 16 + n;
#pragma unroll
                for (int j = 0; j < 4; ++j) {
                    const float s = acc[j];
                    const int rowid = rowb + j;
                    if (s > th[qs] && (rowid >> 4) != qg && bcnt < 16) {
                        const int pk = qg * 32768 + rowid;
#pragma unroll
                        for (int k = 0; k < 16; ++k) if (k == bcnt) bufp[k] = pk;
                        bcnt++;
                    }
                }
            }
            a0 = na0; a1 = na1;
        }
    }
    if (bcnt > 0) {
#pragma unroll
        for (int k = 0; k < 16; ++k) {
            if (k < bcnt) {
                const int pk = bufp[k];
                const int qid = pk >> 15, rid = pk & 32767;
                const int slot = atomicAdd(&cnt[qid], 1);
                if (slot < CAP) ids[(size_t)qid * CAP + slot] = rid;
            }
        }
    }
}

// ---------------------------------------------------------------------------
// Kernel 4: final v2 — coalesced cooperative rescore. 16 lanes per candidate
// row (float4/lane + 4x shfl_xor reduce) instead of 1 thread per row (which
// touched 64 cache lines per wave instruction). 256 blocks x 256 threads.
// ---------------------------------------------------------------------------
__global__ __launch_bounds__(256) void final_kernel(
    const float* __restrict__ x,      // (N,T,F)
    const float* __restrict__ Qf,     // (2048,64)
    const float* __restrict__ Kmat,   // (32768,64)
    const int* __restrict__ cnt,
    const int* __restrict__ ids,
    const float* __restrict__ W1, const float* __restrict__ b1,
    const float* __restrict__ W2, const float* __restrict__ b2,
    float* __restrict__ out)          // (N,)
{
    __shared__ __attribute__((aligned(16))) float Qs[8 * 64];
    __shared__ float sval[8][CAP];    // 30 KB
    __shared__ int cnt_s[8];

    const int t = threadIdx.x;
    const int qbase = blockIdx.x * 8;

    if (t < 128) *(float4*)(Qs + t * 4) = *(const float4*)(Qf + (size_t)qbase * 64 + t * 4);
    if (t < 8) {
        int c = cnt[qbase + t];
        cnt_s[t] = c < CAP ? c : CAP;
    }
    __syncthreads();

    const int grp = t >> 4;   // 0..15: candidate slot within a 16-stride
    const int sl  = t & 15;   // lane within row

    for (int q = 0; q < 8; ++q) {
        const int mc = cnt_s[q];
        const float4 qv = *(const float4*)(Qs + q * 64 + sl * 4);
        const int* idq = ids + (size_t)(qbase + q) * CAP;
        for (int c = grp; c < mc; c += 16) {
            const int id = idq[c];
            const float4 kv = *(const float4*)(Kmat + (size_t)id * 64 + sl * 4);
            float p = qv.x * kv.x + qv.y * kv.y + qv.z * kv.z + qv.w * kv.w;
            p += __shfl_xor(p, 1, 64);
            p += __shfl_xor(p, 2, 64);
            p += __shfl_xor(p, 4, 64);
            p += __shfl_xor(p, 8, 64);
            if (sl == 0) sval[q][c] = p;
        }
    }
    __syncthreads();

    if (t < 8) {
        const int q = t, mc = cnt_s[q];
        float v[TOPKK]; int vid[TOPKK];
#pragma unroll
        for (int r = 0; r < TOPKK; ++r) { v[r] = -3e38f; vid[r] = -1; }
        float vmin = -3e38f; int imin = 0;
        for (int c = 0; c < mc; ++c) {
            const float s = sval[q][c];
            if (s > vmin) {
                const int id = ids[(size_t)(qbase + q) * CAP + c];
#pragma unroll
                for (int r = 0; r < TOPKK; ++r) if (r == imin) { v[r] = s; vid[r] = id; }
                vmin = v[0]; imin = 0;
#pragma unroll
                for (int r = 1; r < TOPKK; ++r) if (v[r] < vmin) { vmin = v[r]; imin = r; }
            }
        }
        float mx = v[0];
#pragma unroll
        for (int r = 1; r < TOPKK; ++r) mx = v[r] > mx ? v[r] : mx;
        float w[TOPKK]; float sum = 0.f;
#pragma unroll
        for (int r = 0; r < TOPKK; ++r) { w[r] = __expf(v[r] - mx); sum += w[r]; }
        const float inv = 1.f / sum;
        float feat[FF];
#pragma unroll
        for (int f = 0; f < FF; ++f) feat[f] = 0.f;
        for (int r = 0; r < TOPKK; ++r) {
            const int wi = vid[r];
            const int m = wi >> 4, l = wi & 15;
            const float* xr = x + ((size_t)m * TT + (48 + l)) * FF;
            const float wr = w[r] * inv;
#pragma unroll
            for (int f = 0; f < FF; ++f) feat[f] += wr * xr[f];
        }
        float o = 0.f;
#pragma unroll
        for (int oo = 0; oo < FF; ++oo) {
            float hh = b1[oo];
#pragma unroll
            for (int f = 0; f < FF; ++f) hh += feat[f] * W1[oo * FF + f];
            hh = hh > 0.f ? hh : 0.01f * hh;
            o += hh * W2[oo];
        }
        o += b2[0];
        out[qbase + t] = o;
    }
}

// ---------------------------------------------------------------------------
extern "C" void kernel_launch(void* const* d_in, const int* in_sizes, int n_in,
                              void* d_out, int out_size, void* d_ws, size_t ws_size,
                              hipStream_t stream) {
    const float* x    = (const float*)d_in[0];
    const float* W_ih = (const float*)d_in[1];
    const float* W_hh = (const float*)d_in[2];
    const float* b_ih = (const float*)d_in[3];
    const float* b_hh = (const float*)d_in[4];
    const float* Wq   = (const float*)d_in[5];
    const float* Wk   = (const float*)d_in[6];
    const float* W1   = (const float*)d_in[7];
    const float* b1   = (const float*)d_in[8];
    const float* W2   = (const float*)d_in[9];
    const float* b2   = (const float*)d_in[10];
    float* outp = (float*)d_out;
    (void)ws_size; (void)n_in; (void)in_sizes; (void)out_size;

    float* h_tail        = (float*)d_ws;                                 // 8 MB
    int*   ids           = (int*)d_ws;                                   // overlay (after prep consumes h_tail)
    float* Kmat          = h_tail + (size_t)2048 * 1024;                 // 8 MB
    unsigned short* Kh   = (unsigned short*)(Kmat + (size_t)32768 * 64); // 4 MB
    float* Qf            = (float*)(Kh + (size_t)32768 * 64);            // 0.5 MB
    unsigned short* Qh   = (unsigned short*)(Qf + (size_t)2048 * 64);    // 0.25 MB
    int*   cnt           = (int*)(Qh + (size_t)2048 * 64);               // 8 KB

    gru_kernel<<<NN / 4, 256, 0, stream>>>(x, W_ih, W_hh, b_ih, b_hh, h_tail, cnt);
    prep_kernel<<<512, 256, 0, stream>>>(h_tail, Wk, Wq, Kmat, Kh, Qf, Qh);
    score_kernel<<<512, 512, 0, stream>>>(Kh, Qh, cnt, ids);
    final_kernel<<<NN / 8, 256, 0, stream>>>(x, Qf, Kmat, cnt, ids, W1, b1, W2, b2, outp);
}

// Round 9
// 281.070 us; speedup vs baseline: 1.1953x; 1.1953x over previous
//
#include <hip/hip_runtime.h>

#define NN 2048
#define TT 64
#define FF 16
#define HH 64
#define LL 16
#define TOPKK 10
#define CAP 960

#define AS 72      // Asp row stride in shorts (144 B)
#define XAS 40     // xa row stride in shorts (80 B)
#define XPS 196    // xp row stride in floats

typedef __bf16 bf16x8 __attribute__((ext_vector_type(8)));
typedef float floatx4 __attribute__((ext_vector_type(4)));

union FragCast { uint4 u; bf16x8 b; unsigned short s[8]; };
union Pack4 { unsigned short s[4]; uint2 u; };

__device__ __forceinline__ unsigned short f2bf(float f) {
    unsigned u = __float_as_uint(f);
    return (unsigned short)((u + 0x7fff + ((u >> 16) & 1)) >> 16);
}
__device__ __forceinline__ float bf2f(unsigned short h) {
    return __uint_as_float(((unsigned)h) << 16);
}
__device__ __forceinline__ void split3(float v, unsigned short& a, unsigned short& b, unsigned short& c) {
    a = f2bf(v); float r = v - bf2f(a);
    b = f2bf(r); float r2 = r - bf2f(b);
    c = f2bf(r2);
}
__device__ __forceinline__ float fsigmoid(float x) {
    return __builtin_amdgcn_rcpf(1.f + __builtin_amdgcn_exp2f(-1.442695041f * x));
}
__device__ __forceinline__ float ftanh(float x) {
    return 1.f - 2.f * __builtin_amdgcn_rcpf(1.f + __builtin_amdgcn_exp2f(2.885390082f * x));
}
__device__ __forceinline__ void async_copy16(const void* g, void* l) {
    __builtin_amdgcn_global_load_lds(
        (const __attribute__((address_space(1))) unsigned int*)g,
        (__attribute__((address_space(3))) unsigned int*)l, 16, 0, 0);
}
#define MFMA16(A, B, C) __builtin_amdgcn_mfma_f32_16x16x32_bf16((A), (B), (C), 0, 0, 0)
#define LIMB6(ACC, A1, A2, A3, W)            \
    ACC = MFMA16((A1), (W)[0], ACC);         \
    ACC = MFMA16((A1), (W)[1], ACC);         \
    ACC = MFMA16((A2), (W)[0], ACC);         \
    ACC = MFMA16((A1), (W)[2], ACC);         \
    ACC = MFMA16((A2), (W)[1], ACC);         \
    ACC = MFMA16((A3), (W)[0], ACC);

// ---------------------------------------------------------------------------
// Kernel 1: MFMA GRU v3 (unchanged). 512 blocks x 256 threads.
// ---------------------------------------------------------------------------
__global__ __launch_bounds__(256, 2) void gru_kernel(
    const float* __restrict__ x,      // (N,T,F)
    const float* __restrict__ W_ih,   // (192,16)
    const float* __restrict__ W_hh,   // (192,64)
    const float* __restrict__ b_ih,   // (192,)
    const float* __restrict__ b_hh,   // (192,)
    float* __restrict__ h_tail,       // (N,16,64)
    int* __restrict__ cnt)            // (2048,) zeroed here
{
    __shared__ __attribute__((aligned(16))) unsigned short Asp[2][3][16 * AS];
    __shared__ __attribute__((aligned(16))) unsigned short xa[3][16 * XAS];
    __shared__ __attribute__((aligned(16))) float xp[16 * XPS];
    __shared__ __attribute__((aligned(16))) float x_lds[4 * TT * FF];

    const int t    = threadIdx.x;
    const int wv   = t >> 6;
    const int lane = t & 63;
    const int nh   = lane & 15;
    const int quad = lane >> 4;
    const int n0   = blockIdx.x * 4;

    if (t < 4) cnt[blockIdx.x * 4 + t] = 0;

    {
        const char* src = (const char*)(x + (size_t)n0 * TT * FF);
        char* dst = (char*)x_lds;
#pragma unroll
        for (int i = 0; i < 4; ++i)
            async_copy16(src + i * 4096 + t * 16, dst + i * 4096 + t * 16);
    }
    {
        unsigned* p = (unsigned*)&Asp[0][0][0];
        for (int i = t; i < 2 * 3 * 16 * AS / 2; i += 256) p[i] = 0;
        unsigned* q = (unsigned*)&xa[0][0];
        for (int i = t; i < 3 * 16 * XAS / 2; i += 256) q[i] = 0;
    }

    const int jb = wv * 16 + nh;
    const float brz = b_ih[jb] + b_hh[jb];
    const float bz  = b_ih[64 + jb] + b_hh[64 + jb];
    const float bxn = b_ih[128 + jb];
    const float bhn = b_hh[128 + jb];

    bf16x8 wf[3][2][3];
#pragma unroll
    for (int nt = 0; nt < 3; ++nt) {
        const int gr = (wv + 4 * nt) * 16 + nh;
#pragma unroll
        for (int kc = 0; kc < 2; ++kc) {
            const float* p = W_hh + gr * 64 + kc * 32 + quad * 8;
            FragCast f1, f2, f3;
#pragma unroll
            for (int i = 0; i < 8; ++i) split3(p[i], f1.s[i], f2.s[i], f3.s[i]);
            wf[nt][kc][0] = f1.b; wf[nt][kc][1] = f2.b; wf[nt][kc][2] = f3.b;
        }
    }
    bf16x8 wfi[3][3];
#pragma unroll
    for (int nt = 0; nt < 3; ++nt) {
        const int gr = (wv + 4 * nt) * 16 + nh;
        FragCast f1, f2, f3;
#pragma unroll
        for (int i = 0; i < 8; ++i) {
            const float v = (quad < 2) ? W_ih[gr * 16 + quad * 8 + i] : 0.f;
            split3(v, f1.s[i], f2.s[i], f3.s[i]);
        }
        wfi[nt][0] = f1.b; wfi[nt][1] = f2.b; wfi[nt][2] = f3.b;
    }

    __syncthreads();

    float hprev = 0.f;

    for (int chunk = 0; chunk < 16; ++chunk) {
        {
            const int row = t >> 4, f = t & 15;
            const int p = row & 3, sl = row >> 2;
            const float xv = x_lds[p * (TT * FF) + (chunk * 4 + sl) * FF + f];
            unsigned short a, b, c; split3(xv, a, b, c);
            xa[0][row * XAS + f] = a;
            xa[1][row * XAS + f] = b;
            xa[2][row * XAS + f] = c;
        }
        __syncthreads();
        {
            floatx4 xacc0 = {0.f,0.f,0.f,0.f}, xacc1 = {0.f,0.f,0.f,0.f}, xacc2 = {0.f,0.f,0.f,0.f};
            const int aoff = nh * XAS + quad * 8;
            FragCast a1, a2, a3;
            a1.u = *(const uint4*)&xa[0][aoff];
            a2.u = *(const uint4*)&xa[1][aoff];
            a3.u = *(const uint4*)&xa[2][aoff];
            LIMB6(xacc0, a1.b, a2.b, a3.b, wfi[0]);
            LIMB6(xacc1, a1.b, a2.b, a3.b, wfi[1]);
            LIMB6(xacc2, a1.b, a2.b, a3.b, wfi[2]);
#pragma unroll
            for (int r = 0; r < 4; ++r) {
                const int m = quad * 4 + r;
                xp[m * XPS + (wv + 0) * 16 + nh] = xacc0[r];
                xp[m * XPS + (wv + 4) * 16 + nh] = xacc1[r];
                xp[m * XPS + (wv + 8) * 16 + nh] = xacc2[r];
            }
        }
        __syncthreads();

#pragma unroll
        for (int si = 0; si < 4; ++si) {
            const int step = chunk * 4 + si;
            const int rb = step & 1, wb = rb ^ 1;
            floatx4 acc0 = {0.f,0.f,0.f,0.f}, acc1 = {0.f,0.f,0.f,0.f}, acc2 = {0.f,0.f,0.f,0.f};
#pragma unroll
            for (int kc = 0; kc < 2; ++kc) {
                const int aoff = nh * AS + kc * 32 + quad * 8;
                FragCast a1, a2, a3;
                a1.u = *(const uint4*)&Asp[rb][0][aoff];
                a2.u = *(const uint4*)&Asp[rb][1][aoff];
                a3.u = *(const uint4*)&Asp[rb][2][aoff];
                LIMB6(acc0, a1.b, a2.b, a3.b, wf[0][kc]);
                LIMB6(acc1, a1.b, a2.b, a3.b, wf[1][kc]);
                LIMB6(acc2, a1.b, a2.b, a3.b, wf[2][kc]);
            }
            {
                const int xrow = si * 4 + quad;
                const float xr = xp[xrow * XPS + jb];
                const float xz = xp[xrow * XPS + 64 + jb];
                const float xn = xp[xrow * XPS + 128 + jb];
                const float rg = fsigmoid(acc0[0] + xr + brz);
                const float zg = fsigmoid(acc1[0] + xz + bz);
                const float ng = ftanh((xn + bxn) + rg * (acc2[0] + bhn));
                const float h  = (1.f - zg) * ng + zg * hprev;
                hprev = h;
                unsigned short la, lb2, lc; split3(h, la, lb2, lc);
                const int ho = (4 * quad) * AS + jb;
                Asp[wb][0][ho] = la;
                Asp[wb][1][ho] = lb2;
                Asp[wb][2][ho] = lc;
                if (step >= TT - LL)
                    h_tail[((size_t)(n0 + quad) * LL + (step - (TT - LL))) * HH + jb] = h;
            }
            __syncthreads();
        }
    }
}

// ---------------------------------------------------------------------------
// Kernel 2: prep v4 (unchanged from R8). 256 blocks x 256 threads.
// ---------------------------------------------------------------------------
__global__ __launch_bounds__(256, 2) void prep_kernel(
    const float* __restrict__ h_tail, // (32768,64)
    const float* __restrict__ Wk,     // (64,64)
    const float* __restrict__ Wq,     // (64,64)
    float* __restrict__ Kmat,         // (32768,64) fp32
    unsigned short* __restrict__ Kh,  // (32768,64) bf16
    float* __restrict__ Qf,           // (2048,64) fp32
    unsigned short* __restrict__ Qh)  // (2048,64) bf16
{
    __shared__ __attribute__((aligned(16))) float Wk_s[64 * 68];
    __shared__ __attribute__((aligned(16))) float Wq_s[64 * 69];
    __shared__ __attribute__((aligned(16))) float h_s[128 * 64];

    const int t = threadIdx.x;
    const size_t rbase = (size_t)blockIdx.x * 128;

    {
        const char* src = (const char*)(h_tail + rbase * 64);
        char* dst = (char*)h_s;
#pragma unroll
        for (int i = 0; i < 8; ++i)
            async_copy16(src + i * 4096 + t * 16, dst + i * 4096 + t * 16);
    }
    for (int c = t; c < 1024; c += 256) {
        const int j = c >> 4, ci = c & 15;
        *(float4*)(Wk_s + j * 68 + ci * 4) = *(const float4*)(Wk + c * 4);
    }
    for (int c = t; c < 4096; c += 256) {
        const int j = c >> 6, i = c & 63;
        Wq_s[j * 69 + i] = Wq[c];
    }
    __syncthreads();

    const int rg = t >> 4;
    const int cg = t & 15;
    float acc[8][4];
#pragma unroll
    for (int rr = 0; rr < 8; ++rr)
#pragma unroll
        for (int c = 0; c < 4; ++c) acc[rr][c] = 0.f;

#pragma unroll
    for (int ci = 0; ci < 16; ++ci) {
        float4 wv[4];
#pragma unroll
        for (int c = 0; c < 4; ++c)
            wv[c] = *(const float4*)(Wk_s + (cg * 4 + c) * 68 + ci * 4);
#pragma unroll
        for (int rr = 0; rr < 8; ++rr) {
            const float4 hv = *(const float4*)(h_s + (rg * 8 + rr) * 64 + ci * 4);
#pragma unroll
            for (int c = 0; c < 4; ++c)
                acc[rr][c] += hv.x * wv[c].x + hv.y * wv[c].y
                            + hv.z * wv[c].z + hv.w * wv[c].w;
        }
    }
#pragma unroll
    for (int rr = 0; rr < 8; ++rr) {
        const size_t row = rbase + rg * 8 + rr;
        float4 o; o.x = acc[rr][0]; o.y = acc[rr][1]; o.z = acc[rr][2]; o.w = acc[rr][3];
        *(float4*)(Kmat + row * 64 + cg * 4) = o;
        Pack4 p;
#pragma unroll
        for (int c = 0; c < 4; ++c) p.s[c] = f2bf(acc[rr][c]);
        *(uint2*)(Kh + row * 64 + cg * 4) = p.u;
    }

    {
        const int j = t & 63;
#pragma unroll
        for (int k = 0; k < 2; ++k) {
            const int s = (t >> 6) * 2 + k;
            const float* hr = h_s + (s * 16 + 15) * 64;
            float a0 = 0.f, a1 = 0.f;
#pragma unroll
            for (int i = 0; i < 64; i += 2) {
                a0 += hr[i] * Wq_s[j * 69 + i];
                a1 += hr[i + 1] * Wq_s[j * 69 + i + 1];
            }
            const float a = a0 + a1;
            const size_t qi = (size_t)(blockIdx.x * 8 + s) * 64 + j;
            Qf[qi] = a;
            Qh[qi] = f2bf(a);
        }
    }
}

// ---------------------------------------------------------------------------
// Kernel 3: MFMA scores + threshold filter, Qtile=64 (unchanged).
// ---------------------------------------------------------------------------
__global__ __launch_bounds__(512, 4) void score_kernel(
    const unsigned short* __restrict__ Kh,  // (32768,64) bf16
    const unsigned short* __restrict__ Qh,  // (2048,64) bf16
    int* __restrict__ cnt,                  // (2048,)
    int* __restrict__ ids)                  // (2048, CAP)
{
    __shared__ float stat_s[8][4][16];
    __shared__ float stat_q[8][4][16];
    __shared__ float th_s[64];

    const int t    = threadIdx.x;
    const int wave = t >> 6;
    const int lane = t & 63;
    const int n    = lane & 15;
    const int quad = lane >> 4;

    const int qgroup = blockIdx.x >> 4;
    const int split  = blockIdx.x & 15;
    const int tile0  = split * 128 + wave * 16;

    FragCast bq[4][2];
#pragma unroll
    for (int qs = 0; qs < 4; ++qs) {
        const int qg = qgroup * 64 + qs * 16 + n;
        bq[qs][0].u = *(const uint4*)(Qh + (size_t)qg * 64 + quad * 8);
        bq[qs][1].u = *(const uint4*)(Qh + (size_t)qg * 64 + 32 + quad * 8);
    }

    float ssum[4] = {0.f,0.f,0.f,0.f}, ssq[4] = {0.f,0.f,0.f,0.f};
    for (int i = 0; i < 8; ++i) {
        const unsigned short* r = Kh + (size_t)((tile0 + i) * 16 + n) * 64;
        FragCast a0, a1;
        a0.u = *(const uint4*)(r + quad * 8);
        a1.u = *(const uint4*)(r + 32 + quad * 8);
#pragma unroll
        for (int qs = 0; qs < 4; ++qs) {
            floatx4 acc = {0.f, 0.f, 0.f, 0.f};
            acc = MFMA16(a0.b, bq[qs][0].b, acc);
            acc = MFMA16(a1.b, bq[qs][1].b, acc);
#pragma unroll
            for (int j = 0; j < 4; ++j) { ssum[qs] += acc[j]; ssq[qs] += acc[j] * acc[j]; }
        }
    }
#pragma unroll
    for (int qs = 0; qs < 4; ++qs) {
        ssum[qs] += __shfl_xor(ssum[qs], 16, 64); ssq[qs] += __shfl_xor(ssq[qs], 16, 64);
        ssum[qs] += __shfl_xor(ssum[qs], 32, 64); ssq[qs] += __shfl_xor(ssq[qs], 32, 64);
    }
    if (lane < 16) {
#pragma unroll
        for (int qs = 0; qs < 4; ++qs) { stat_s[wave][qs][n] = ssum[qs]; stat_q[wave][qs][n] = ssq[qs]; }
    }
    __syncthreads();
    if (t < 64) {
        const int qs = t >> 4, c = t & 15;
        float S = 0.f, S2 = 0.f;
#pragma unroll
        for (int w = 0; w < 8; ++w) { S += stat_s[w][qs][c]; S2 += stat_q[w][qs][c]; }
        const float inv = 1.f / 1024.f;
        const float mu = S * inv;
        float var = S2 * inv - mu * mu;
        var = var > 0.f ? var : 0.f;
        th_s[t] = mu + 2.6f * __fsqrt_rn(var);
    }
    __syncthreads();
    float th[4];
#pragma unroll
    for (int qs = 0; qs < 4; ++qs) th[qs] = th_s[qs * 16 + n];

    int bufp[16];
    int bcnt = 0;
    {
        FragCast a0, a1, na0, na1;
        const unsigned short* r0 = Kh + (size_t)(tile0 * 16 + n) * 64;
        a0.u = *(const uint4*)(r0 + quad * 8);
        a1.u = *(const uint4*)(r0 + 32 + quad * 8);
        for (int i = 0; i < 16; ++i) {
            if (i + 1 < 16) {
                const unsigned short* r = Kh + (size_t)((tile0 + i + 1) * 16 + n) * 64;
                na0.u = *(const uint4*)(r + quad * 8);
                na1.u = *(const uint4*)(r + 32 + quad * 8);
            }
            const int rowb = (tile0 + i) * 16 + quad * 4;
#pragma unroll
            for (int qs = 0; qs < 4; ++qs) {
                floatx4 acc = {0.f, 0.f, 0.f, 0.f};
                acc = MFMA16(a0.b, bq[qs][0].b, acc);
                acc = MFMA16(a1.b, bq[qs][1].b, acc);
                const int qg = qgroup * 64 + qs * 16 + n;
#pragma unroll
                for (int j = 0; j < 4; ++j) {
                    const float s = acc[j];
                    const int rowid = rowb + j;
                    if (s > th[qs] && (rowid >> 4) != qg && bcnt < 16) {
                        const int pk = qg * 32768 + rowid;
#pragma unroll
                        for (int k = 0; k < 16; ++k) if (k == bcnt) bufp[k] = pk;
                        bcnt++;
                    }
                }
            }
            a0 = na0; a1 = na1;
        }
    }
    if (bcnt > 0) {
#pragma unroll
        for (int k = 0; k < 16; ++k) {
            if (k < bcnt) {
                const int pk = bufp[k];
                const int qid = pk >> 15, rid = pk & 32767;
                const int slot = atomicAdd(&cnt[qid], 1);
                if (slot < CAP) ids[(size_t)qid * CAP + slot] = rid;
            }
        }
    }
}

// ---------------------------------------------------------------------------
// Kernel 4: final v3.1 — wave-per-query, WITH lane-0 broadcast of the merged
// top-10 (the R8 bug: the xor-16/32 butterfly is sl-preserving, so only
// holder lanes had the merged list; ranks 1..9 gathered nothing).
// ---------------------------------------------------------------------------
__global__ __launch_bounds__(512) void final_kernel(
    const float* __restrict__ x,      // (N,T,F)
    const float* __restrict__ Qf,     // (2048,64)
    const float* __restrict__ Kmat,   // (32768,64)
    const int* __restrict__ cnt,
    const int* __restrict__ ids,
    const float* __restrict__ W1, const float* __restrict__ b1,
    const float* __restrict__ W2, const float* __restrict__ b2,
    float* __restrict__ out)          // (N,)
{
    const int t    = threadIdx.x;
    const int w    = t >> 6;
    const int lane = t & 63;
    const int grp  = lane >> 4;
    const int sl   = lane & 15;
    const int q    = blockIdx.x * 8 + w;

    const int mc0 = cnt[q];
    const int mc  = mc0 < CAP ? mc0 : CAP;
    const float4 qv = *(const float4*)(Qf + (size_t)q * 64 + sl * 4);
    const int* idq = ids + (size_t)q * CAP;

    float v[TOPKK]; int vid[TOPKK];
#pragma unroll
    for (int r = 0; r < TOPKK; ++r) { v[r] = -3e38f; vid[r] = -1; }
    float vmin = -3e38f; int imin = 0;

    for (int c = grp; c < mc; c += 4) {
        const int id = idq[c];
        const float4 kv = *(const float4*)(Kmat + (size_t)id * 64 + sl * 4);
        float p = qv.x * kv.x + qv.y * kv.y + qv.z * kv.z + qv.w * kv.w;
        p += __shfl_xor(p, 1, 64);
        p += __shfl_xor(p, 2, 64);
        p += __shfl_xor(p, 4, 64);
        p += __shfl_xor(p, 8, 64);
        if (sl == 0 && p > vmin) {
#pragma unroll
            for (int r = 0; r < TOPKK; ++r) if (r == imin) { v[r] = p; vid[r] = id; }
            vmin = v[0]; imin = 0;
#pragma unroll
            for (int r = 1; r < TOPKK; ++r) if (v[r] < vmin) { vmin = v[r]; imin = r; }
        }
    }

    // 10-round merge across holder lanes (0,16,32,48)
    float topv[TOPKK]; int topi[TOPKK];
    unsigned used = 0;
    for (int r = 0; r < TOPKK; ++r) {
        float bv = -3e38f; int bi = -1, bs = -1;
#pragma unroll
        for (int s = 0; s < TOPKK; ++s)
            if (!((used >> s) & 1) && v[s] > bv) { bv = v[s]; bi = vid[s]; bs = s; }
        const float mybv = bv; const int mybi = bi;
#pragma unroll
        for (int st = 16; st <= 32; st <<= 1) {
            const float ov = __shfl_xor(bv, st, 64);
            const int   oi = __shfl_xor(bi, st, 64);
            if (ov > bv || (ov == bv && oi > bi)) { bv = ov; bi = oi; }
        }
        topv[r] = bv; topi[r] = bi;
        if (bs >= 0 && mybv == bv && mybi == bi) used |= (1u << bs);
    }
    // BROADCAST the merged list from lane 0 to all lanes (the R8 fix)
#pragma unroll
    for (int r = 0; r < TOPKK; ++r) {
        topv[r] = __shfl(topv[r], 0, 64);
        topi[r] = __shfl(topi[r], 0, 64);
    }

    // softmax weights (identical on all lanes now)
    float mx = topv[0];
#pragma unroll
    for (int r = 1; r < TOPKK; ++r) mx = topv[r] > mx ? topv[r] : mx;
    float wgt[TOPKK]; float sw = 0.f;
#pragma unroll
    for (int r = 0; r < TOPKK; ++r) {
        wgt[r] = (topi[r] >= 0) ? __expf(topv[r] - mx) : 0.f;
        sw += wgt[r];
    }
    const float inv = 1.f / sw;

    // gather: lane r (<10) loads its leader-feature row, scaled
    float4 f0 = {0,0,0,0}, f1 = {0,0,0,0}, f2 = {0,0,0,0}, f3 = {0,0,0,0};
    if (lane < TOPKK && topi[lane] >= 0) {
        const int wi = topi[lane];
        const float* xr = x + ((size_t)(wi >> 4) * TT + 48 + (wi & 15)) * FF;
        const float s = wgt[lane] * inv;
        float4 a = *(const float4*)(xr);
        float4 b = *(const float4*)(xr + 4);
        float4 cc = *(const float4*)(xr + 8);
        float4 d = *(const float4*)(xr + 12);
        f0.x = s * a.x; f0.y = s * a.y; f0.z = s * a.z; f0.w = s * a.w;
        f1.x = s * b.x; f1.y = s * b.y; f1.z = s * b.z; f1.w = s * b.w;
        f2.x = s * cc.x; f2.y = s * cc.y; f2.z = s * cc.z; f2.w = s * cc.w;
        f3.x = s * d.x; f3.y = s * d.y; f3.z = s * d.z; f3.w = s * d.w;
    }
#pragma unroll
    for (int st = 1; st <= 8; st <<= 1) {
        f0.x += __shfl_xor(f0.x, st, 64); f0.y += __shfl_xor(f0.y, st, 64);
        f0.z += __shfl_xor(f0.z, st, 64); f0.w += __shfl_xor(f0.w, st, 64);
        f1.x += __shfl_xor(f1.x, st, 64); f1.y += __shfl_xor(f1.y, st, 64);
        f1.z += __shfl_xor(f1.z, st, 64); f1.w += __shfl_xor(f1.w, st, 64);
        f2.x += __shfl_xor(f2.x, st, 64); f2.y += __shfl_xor(f2.y, st, 64);
        f2.z += __shfl_xor(f2.z, st, 64); f2.w += __shfl_xor(f2.w, st, 64);
        f3.x += __shfl_xor(f3.x, st, 64); f3.y += __shfl_xor(f3.y, st, 64);
        f3.z += __shfl_xor(f3.z, st, 64); f3.w += __shfl_xor(f3.w, st, 64);
    }

    // MLP: lane oo (<16) computes hidden unit oo
    float o = 0.f;
    if (lane < 16) {
        const float* w1r = W1 + lane * 16;
        float hh = b1[lane]
            + f0.x * w1r[0]  + f0.y * w1r[1]  + f0.z * w1r[2]  + f0.w * w1r[3]
            + f1.x * w1r[4]  + f1.y * w1r[5]  + f1.z * w1r[6]  + f1.w * w1r[7]
            + f2.x * w1r[8]  + f2.y * w1r[9]  + f2.z * w1r[10] + f2.w * w1r[11]
            + f3.x * w1r[12] + f3.y * w1r[13] + f3.z * w1r[14] + f3.w * w1r[15];
        hh = hh > 0.f ? hh : 0.01f * hh;
        o = hh * W2[lane];
    }
#pragma unroll
    for (int st = 1; st <= 8; st <<= 1) o += __shfl_xor(o, st, 64);
    if (lane == 0) out[q] = o + b2[0];
}

// ---------------------------------------------------------------------------
extern "C" void kernel_launch(void* const* d_in, const int* in_sizes, int n_in,
                              void* d_out, int out_size, void* d_ws, size_t ws_size,
                              hipStream_t stream) {
    const float* x    = (const float*)d_in[0];
    const float* W_ih = (const float*)d_in[1];
    const float* W_hh = (const float*)d_in[2];
    const float* b_ih = (const float*)d_in[3];
    const float* b_hh = (const float*)d_in[4];
    const float* Wq   = (const float*)d_in[5];
    const float* Wk   = (const float*)d_in[6];
    const float* W1   = (const float*)d_in[7];
    const float* b1   = (const float*)d_in[8];
    const float* W2   = (const float*)d_in[9];
    const float* b2   = (const float*)d_in[10];
    float* outp = (float*)d_out;
    (void)ws_size; (void)n_in; (void)in_sizes; (void)out_size;

    float* h_tail        = (float*)d_ws;                                 // 8 MB
    int*   ids           = (int*)d_ws;                                   // overlay (after prep consumes h_tail)
    float* Kmat          = h_tail + (size_t)2048 * 1024;                 // 8 MB
    unsigned short* Kh   = (unsigned short*)(Kmat + (size_t)32768 * 64); // 4 MB
    float* Qf            = (float*)(Kh + (size_t)32768 * 64);            // 0.5 MB
    unsigned short* Qh   = (unsigned short*)(Qf + (size_t)2048 * 64);    // 0.25 MB
    int*   cnt           = (int*)(Qh + (size_t)2048 * 64);               // 8 KB

    gru_kernel<<<NN / 4, 256, 0, stream>>>(x, W_ih, W_hh, b_ih, b_hh, h_tail, cnt);
    prep_kernel<<<256, 256, 0, stream>>>(h_tail, Wk, Wq, Kmat, Kh, Qf, Qh);
    score_kernel<<<512, 512, 0, stream>>>(Kh, Qh, cnt, ids);
    final_kernel<<<NN / 8, 512, 0, stream>>>(x, Qf, Kmat, cnt, ids, W1, b1, W2, b2, outp);
}

// Round 10
// 256.710 us; speedup vs baseline: 1.3087x; 1.0949x over previous
//
#include <hip/hip_runtime.h>

#define NN 2048
#define TT 64
#define FF 16
#define HH 64
#define LL 16
#define TOPKK 10
#define CAP 960

#define AS 72      // Asp row stride in shorts (144 B)
#define XAS 40     // xa row stride in shorts (80 B)
#define XPS 196    // xp row stride in floats

typedef __bf16 bf16x8 __attribute__((ext_vector_type(8)));
typedef float floatx4 __attribute__((ext_vector_type(4)));

union FragCast { uint4 u; bf16x8 b; unsigned short s[8]; };
union Pack4 { unsigned short s[4]; uint2 u; };

__device__ __forceinline__ unsigned short f2bf(float f) {
    unsigned u = __float_as_uint(f);
    return (unsigned short)((u + 0x7fff + ((u >> 16) & 1)) >> 16);
}
__device__ __forceinline__ float bf2f(unsigned short h) {
    return __uint_as_float(((unsigned)h) << 16);
}
__device__ __forceinline__ void split3(float v, unsigned short& a, unsigned short& b, unsigned short& c) {
    a = f2bf(v); float r = v - bf2f(a);
    b = f2bf(r); float r2 = r - bf2f(b);
    c = f2bf(r2);
}
__device__ __forceinline__ float fsigmoid(float x) {
    return __builtin_amdgcn_rcpf(1.f + __builtin_amdgcn_exp2f(-1.442695041f * x));
}
__device__ __forceinline__ float ftanh(float x) {
    return 1.f - 2.f * __builtin_amdgcn_rcpf(1.f + __builtin_amdgcn_exp2f(2.885390082f * x));
}
__device__ __forceinline__ void async_copy16(const void* g, void* l) {
    __builtin_amdgcn_global_load_lds(
        (const __attribute__((address_space(1))) unsigned int*)g,
        (__attribute__((address_space(3))) unsigned int*)l, 16, 0, 0);
}
#define MFMA16(A, B, C) __builtin_amdgcn_mfma_f32_16x16x32_bf16((A), (B), (C), 0, 0, 0)

// ---------------------------------------------------------------------------
// Kernel 1: MFMA GRU v4. 512 blocks x 256 threads, 4 samples/block.
// Change vs v3: 3-limb product set split into A/B accumulator halves with
// product-major source interleave -> 12 independent MFMA chains per SIMD
// (was 3 x 12-deep dependent chains/wave at ~13 cyc/MFMA exposed latency).
// ---------------------------------------------------------------------------
__global__ __launch_bounds__(256, 2) void gru_kernel(
    const float* __restrict__ x,      // (N,T,F)
    const float* __restrict__ W_ih,   // (192,16)
    const float* __restrict__ W_hh,   // (192,64)
    const float* __restrict__ b_ih,   // (192,)
    const float* __restrict__ b_hh,   // (192,)
    float* __restrict__ h_tail,       // (N,16,64)
    int* __restrict__ cnt)            // (2048,) zeroed here
{
    __shared__ __attribute__((aligned(16))) unsigned short Asp[2][3][16 * AS];
    __shared__ __attribute__((aligned(16))) unsigned short xa[3][16 * XAS];
    __shared__ __attribute__((aligned(16))) float xp[16 * XPS];
    __shared__ __attribute__((aligned(16))) float x_lds[4 * TT * FF];

    const int t    = threadIdx.x;
    const int wv   = t >> 6;
    const int lane = t & 63;
    const int nh   = lane & 15;
    const int quad = lane >> 4;
    const int n0   = blockIdx.x * 4;

    if (t < 4) cnt[blockIdx.x * 4 + t] = 0;

    {
        const char* src = (const char*)(x + (size_t)n0 * TT * FF);
        char* dst = (char*)x_lds;
#pragma unroll
        for (int i = 0; i < 4; ++i)
            async_copy16(src + i * 4096 + t * 16, dst + i * 4096 + t * 16);
    }
    {
        unsigned* p = (unsigned*)&Asp[0][0][0];
        for (int i = t; i < 2 * 3 * 16 * AS / 2; i += 256) p[i] = 0;
        unsigned* q = (unsigned*)&xa[0][0];
        for (int i = t; i < 3 * 16 * XAS / 2; i += 256) q[i] = 0;
    }

    const int jb = wv * 16 + nh;
    const float brz = b_ih[jb] + b_hh[jb];
    const float bz  = b_ih[64 + jb] + b_hh[64 + jb];
    const float bxn = b_ih[128 + jb];
    const float bhn = b_hh[128 + jb];

    bf16x8 wf[3][2][3];
#pragma unroll
    for (int nt = 0; nt < 3; ++nt) {
        const int gr = (wv + 4 * nt) * 16 + nh;
#pragma unroll
        for (int kc = 0; kc < 2; ++kc) {
            const float* p = W_hh + gr * 64 + kc * 32 + quad * 8;
            FragCast f1, f2, f3;
#pragma unroll
            for (int i = 0; i < 8; ++i) split3(p[i], f1.s[i], f2.s[i], f3.s[i]);
            wf[nt][kc][0] = f1.b; wf[nt][kc][1] = f2.b; wf[nt][kc][2] = f3.b;
        }
    }
    bf16x8 wfi[3][3];
#pragma unroll
    for (int nt = 0; nt < 3; ++nt) {
        const int gr = (wv + 4 * nt) * 16 + nh;
        FragCast f1, f2, f3;
#pragma unroll
        for (int i = 0; i < 8; ++i) {
            const float v = (quad < 2) ? W_ih[gr * 16 + quad * 8 + i] : 0.f;
            split3(v, f1.s[i], f2.s[i], f3.s[i]);
        }
        wfi[nt][0] = f1.b; wfi[nt][1] = f2.b; wfi[nt][2] = f3.b;
    }

    __syncthreads();

    float hprev = 0.f;

    for (int chunk = 0; chunk < 16; ++chunk) {
        {
            const int row = t >> 4, f = t & 15;
            const int p = row & 3, sl = row >> 2;
            const float xv = x_lds[p * (TT * FF) + (chunk * 4 + sl) * FF + f];
            unsigned short a, b, c; split3(xv, a, b, c);
            xa[0][row * XAS + f] = a;
            xa[1][row * XAS + f] = b;
            xa[2][row * XAS + f] = c;
        }
        __syncthreads();
        // xp = x_chunk @ W_ih^T, product-major A/B split (9+9 MFMAs)
        {
            floatx4 xA0 = {0,0,0,0}, xB0 = {0,0,0,0};
            floatx4 xA1 = {0,0,0,0}, xB1 = {0,0,0,0};
            floatx4 xA2 = {0,0,0,0}, xB2 = {0,0,0,0};
            const int aoff = nh * XAS + quad * 8;
            FragCast a1, a2, a3;
            a1.u = *(const uint4*)&xa[0][aoff];
            a2.u = *(const uint4*)&xa[1][aoff];
            a3.u = *(const uint4*)&xa[2][aoff];
            xA0 = MFMA16(a1.b, wfi[0][0], xA0); xA1 = MFMA16(a1.b, wfi[1][0], xA1); xA2 = MFMA16(a1.b, wfi[2][0], xA2);
            xB0 = MFMA16(a1.b, wfi[0][1], xB0); xB1 = MFMA16(a1.b, wfi[1][1], xB1); xB2 = MFMA16(a1.b, wfi[2][1], xB2);
            xB0 = MFMA16(a2.b, wfi[0][0], xB0); xB1 = MFMA16(a2.b, wfi[1][0], xB1); xB2 = MFMA16(a2.b, wfi[2][0], xB2);
            xA0 = MFMA16(a1.b, wfi[0][2], xA0); xA1 = MFMA16(a1.b, wfi[1][2], xA1); xA2 = MFMA16(a1.b, wfi[2][2], xA2);
            xA0 = MFMA16(a2.b, wfi[0][1], xA0); xA1 = MFMA16(a2.b, wfi[1][1], xA1); xA2 = MFMA16(a2.b, wfi[2][1], xA2);
            xB0 = MFMA16(a3.b, wfi[0][0], xB0); xB1 = MFMA16(a3.b, wfi[1][0], xB1); xB2 = MFMA16(a3.b, wfi[2][0], xB2);
#pragma unroll
            for (int r = 0; r < 4; ++r) {
                const int m = quad * 4 + r;
                xp[m * XPS + (wv + 0) * 16 + nh] = xA0[r] + xB0[r];
                xp[m * XPS + (wv + 4) * 16 + nh] = xA1[r] + xB1[r];
                xp[m * XPS + (wv + 8) * 16 + nh] = xA2[r] + xB2[r];
            }
        }
        __syncthreads();

#pragma unroll
        for (int si = 0; si < 4; ++si) {
            const int step = chunk * 4 + si;
            const int rb = step & 1, wb = rb ^ 1;
            floatx4 aA0 = {0,0,0,0}, aB0 = {0,0,0,0};
            floatx4 aA1 = {0,0,0,0}, aB1 = {0,0,0,0};
            floatx4 aA2 = {0,0,0,0}, aB2 = {0,0,0,0};
#pragma unroll
            for (int kc = 0; kc < 2; ++kc) {
                const int aoff = nh * AS + kc * 32 + quad * 8;
                FragCast a1, a2, a3;
                a1.u = *(const uint4*)&Asp[rb][0][aoff];
                a2.u = *(const uint4*)&Asp[rb][1][aoff];
                a3.u = *(const uint4*)&Asp[rb][2][aoff];
                // product-major: P0..P5 x 3 gates; chainA = {P0,P3,P4}, chainB = {P1,P2,P5}
                aA0 = MFMA16(a1.b, wf[0][kc][0], aA0); aA1 = MFMA16(a1.b, wf[1][kc][0], aA1); aA2 = MFMA16(a1.b, wf[2][kc][0], aA2);
                aB0 = MFMA16(a1.b, wf[0][kc][1], aB0); aB1 = MFMA16(a1.b, wf[1][kc][1], aB1); aB2 = MFMA16(a1.b, wf[2][kc][1], aB2);
                aB0 = MFMA16(a2.b, wf[0][kc][0], aB0); aB1 = MFMA16(a2.b, wf[1][kc][0], aB1); aB2 = MFMA16(a2.b, wf[2][kc][0], aB2);
                aA0 = MFMA16(a1.b, wf[0][kc][2], aA0); aA1 = MFMA16(a1.b, wf[1][kc][2], aA1); aA2 = MFMA16(a1.b, wf[2][kc][2], aA2);
                aA0 = MFMA16(a2.b, wf[0][kc][1], aA0); aA1 = MFMA16(a2.b, wf[1][kc][1], aA1); aA2 = MFMA16(a2.b, wf[2][kc][1], aA2);
                aB0 = MFMA16(a3.b, wf[0][kc][0], aB0); aB1 = MFMA16(a3.b, wf[1][kc][0], aB1); aB2 = MFMA16(a3.b, wf[2][kc][0], aB2);
            }
            {
                const int xrow = si * 4 + quad;
                const float xr = xp[xrow * XPS + jb];
                const float xz = xp[xrow * XPS + 64 + jb];
                const float xn = xp[xrow * XPS + 128 + jb];
                const float rgt = fsigmoid((aA0[0] + aB0[0]) + xr + brz);
                const float zgt = fsigmoid((aA1[0] + aB1[0]) + xz + bz);
                const float ngt = ftanh((xn + bxn) + rgt * ((aA2[0] + aB2[0]) + bhn));
                const float h  = (1.f - zgt) * ngt + zgt * hprev;
                hprev = h;
                unsigned short la, lb2, lc; split3(h, la, lb2, lc);
                const int ho = (4 * quad) * AS + jb;
                Asp[wb][0][ho] = la;
                Asp[wb][1][ho] = lb2;
                Asp[wb][2][ho] = lc;
                if (step >= TT - LL)
                    h_tail[((size_t)(n0 + quad) * LL + (step - (TT - LL))) * HH + jb] = h;
            }
            __syncthreads();
        }
    }
}

// ---------------------------------------------------------------------------
// Kernel 2: prep v5 — 512 blocks x 256 threads, 64 K-rows (4 samples)/block,
// 2 blocks/CU. LDS bank geometry fixed: Wk chunk-XOR swizzle (was 8-way
// conflict at stride 68 column reads), h staged to stride-68 (2-way = free).
// ---------------------------------------------------------------------------
__global__ __launch_bounds__(256, 2) void prep_kernel(
    const float* __restrict__ h_tail, // (32768,64)
    const float* __restrict__ Wk,     // (64,64)
    const float* __restrict__ Wq,     // (64,64)
    float* __restrict__ Kmat,         // (32768,64) fp32
    unsigned short* __restrict__ Kh,  // (32768,64) bf16
    float* __restrict__ Qf,           // (2048,64) fp32
    unsigned short* __restrict__ Qh)  // (2048,64) bf16
{
    __shared__ __attribute__((aligned(16))) float Wk_s[64 * 68];  // chunk-XOR swizzled
    __shared__ __attribute__((aligned(16))) float Wq_s[64 * 69];  // scalar reads, 2-way free
    __shared__ __attribute__((aligned(16))) float h_s[64 * 68];   // stride-68: 2-way free

    const int t = threadIdx.x;
    const size_t rbase = (size_t)blockIdx.x * 64;   // 4 samples * 16 lags

    // stage h (16 KB) coalesced -> padded stride 68
#pragma unroll
    for (int k = 0; k < 4; ++k) {
        const int idx = t + k * 256;                // 1024 float4s
        const int j = idx >> 4, ci = idx & 15;
        *(float4*)(h_s + j * 68 + ci * 4) = *(const float4*)(h_tail + (rbase + j) * 64 + ci * 4);
    }
    // stage Wk with chunk-XOR swizzle: chunk ci of row j at (ci ^ (j>>2)) * 4
    for (int c = t; c < 1024; c += 256) {
        const int j = c >> 4, ci = c & 15;
        *(float4*)(Wk_s + j * 68 + ((ci ^ (j >> 2)) << 2)) = *(const float4*)(Wk + c * 4);
    }
    // stage Wq (stride 69), coalesced scalar
    for (int c = t; c < 4096; c += 256) {
        const int j = c >> 6, i = c & 63;
        Wq_s[j * 69 + i] = Wq[c];
    }
    __syncthreads();

    const int rg = t >> 4;        // rows rg*4 .. +3
    const int cg = t & 15;        // cols cg*4 .. +3
    float acc[4][4];
#pragma unroll
    for (int r = 0; r < 4; ++r)
#pragma unroll
        for (int c = 0; c < 4; ++c) acc[r][c] = 0.f;

#pragma unroll
    for (int ci = 0; ci < 16; ++ci) {
        float4 wv[4];
#pragma unroll
        for (int c = 0; c < 4; ++c) {
            const int j = cg * 4 + c;               // j>>2 == cg
            wv[c] = *(const float4*)(Wk_s + j * 68 + ((ci ^ cg) << 2));
        }
#pragma unroll
        for (int r = 0; r < 4; ++r) {
            const float4 hv = *(const float4*)(h_s + (rg * 4 + r) * 68 + ci * 4);
#pragma unroll
            for (int c = 0; c < 4; ++c)
                acc[r][c] += hv.x * wv[c].x + hv.y * wv[c].y
                           + hv.z * wv[c].z + hv.w * wv[c].w;
        }
    }
#pragma unroll
    for (int r = 0; r < 4; ++r) {
        const size_t row = rbase + rg * 4 + r;
        float4 o; o.x = acc[r][0]; o.y = acc[r][1]; o.z = acc[r][2]; o.w = acc[r][3];
        *(float4*)(Kmat + row * 64 + cg * 4) = o;
        Pack4 p;
#pragma unroll
        for (int c = 0; c < 4; ++c) p.s[c] = f2bf(acc[r][c]);
        *(uint2*)(Kh + row * 64 + cg * 4) = p.u;
    }

    // Q: 4 samples x 64 cols, one per thread. h row is wave-uniform broadcast.
    {
        const int s = t >> 6, j = t & 63;
        const float* hr = h_s + (s * 16 + 15) * 68;
        float a0 = 0.f, a1 = 0.f;
#pragma unroll
        for (int i = 0; i < 64; i += 2) {
            a0 += hr[i] * Wq_s[j * 69 + i];
            a1 += hr[i + 1] * Wq_s[j * 69 + i + 1];
        }
        const float a = a0 + a1;
        const size_t qi = (size_t)(blockIdx.x * 4 + s) * 64 + j;
        Qf[qi] = a;
        Qh[qi] = f2bf(a);
    }
}

// ---------------------------------------------------------------------------
// Kernel 3: MFMA scores + threshold filter v2. Qtile=64, 512 blocks x 512.
// Change: immediate atomic emit per candidate (was: 16-cndmask register
// buffer insert + flush loop — ~20 VALU per emit under divergence).
// ---------------------------------------------------------------------------
__global__ __launch_bounds__(512, 4) void score_kernel(
    const unsigned short* __restrict__ Kh,  // (32768,64) bf16
    const unsigned short* __restrict__ Qh,  // (2048,64) bf16
    int* __restrict__ cnt,                  // (2048,)
    int* __restrict__ ids)                  // (2048, CAP)
{
    __shared__ float stat_s[8][4][16];
    __shared__ float stat_q[8][4][16];
    __shared__ float th_s[64];

    const int t    = threadIdx.x;
    const int wave = t >> 6;
    const int lane = t & 63;
    const int n    = lane & 15;
    const int quad = lane >> 4;

    const int qgroup = blockIdx.x >> 4;
    const int split  = blockIdx.x & 15;
    const int tile0  = split * 128 + wave * 16;

    FragCast bq[4][2];
#pragma unroll
    for (int qs = 0; qs < 4; ++qs) {
        const int qg = qgroup * 64 + qs * 16 + n;
        bq[qs][0].u = *(const uint4*)(Qh + (size_t)qg * 64 + quad * 8);
        bq[qs][1].u = *(const uint4*)(Qh + (size_t)qg * 64 + 32 + quad * 8);
    }

    float ssum[4] = {0.f,0.f,0.f,0.f}, ssq[4] = {0.f,0.f,0.f,0.f};
    for (int i = 0; i < 8; ++i) {
        const unsigned short* r = Kh + (size_t)((tile0 + i) * 16 + n) * 64;
        FragCast a0, a1;
        a0.u = *(const uint4*)(r + quad * 8);
        a1.u = *(const uint4*)(r + 32 + quad * 8);
#pragma unroll
        for (int qs = 0; qs < 4; ++qs) {
            floatx4 acc = {0.f, 0.f, 0.f, 0.f};
            acc = MFMA16(a0.b, bq[qs][0].b, acc);
            acc = MFMA16(a1.b, bq[qs][1].b, acc);
#pragma unroll
            for (int j = 0; j < 4; ++j) { ssum[qs] += acc[j]; ssq[qs] += acc[j] * acc[j]; }
        }
    }
#pragma unroll
    for (int qs = 0; qs < 4; ++qs) {
        ssum[qs] += __shfl_xor(ssum[qs], 16, 64); ssq[qs] += __shfl_xor(ssq[qs], 16, 64);
        ssum[qs] += __shfl_xor(ssum[qs], 32, 64); ssq[qs] += __shfl_xor(ssq[qs], 32, 64);
    }
    if (lane < 16) {
#pragma unroll
        for (int qs = 0; qs < 4; ++qs) { stat_s[wave][qs][n] = ssum[qs]; stat_q[wave][qs][n] = ssq[qs]; }
    }
    __syncthreads();
    if (t < 64) {
        const int qs = t >> 4, c = t & 15;
        float S = 0.f, S2 = 0.f;
#pragma unroll
        for (int w = 0; w < 8; ++w) { S += stat_s[w][qs][c]; S2 += stat_q[w][qs][c]; }
        const float inv = 1.f / 1024.f;
        const float mu = S * inv;
        float var = S2 * inv - mu * mu;
        var = var > 0.f ? var : 0.f;
        th_s[t] = mu + 2.6f * __fsqrt_rn(var);
    }
    __syncthreads();
    float th[4];
#pragma unroll
    for (int qs = 0; qs < 4; ++qs) th[qs] = th_s[qs * 16 + n];

    // Pass B: 16 tiles, immediate atomic emit above threshold
    {
        FragCast a0, a1, na0, na1;
        const unsigned short* r0 = Kh + (size_t)(tile0 * 16 + n) * 64;
        a0.u = *(const uint4*)(r0 + quad * 8);
        a1.u = *(const uint4*)(r0 + 32 + quad * 8);
        for (int i = 0; i < 16; ++i) {
            if (i + 1 < 16) {
                const unsigned short* r = Kh + (size_t)((tile0 + i + 1) * 16 + n) * 64;
                na0.u = *(const uint4*)(r + quad * 8);
                na1.u = *(const uint4*)(r + 32 + quad * 8);
            }
            const int rowb = (tile0 + i) * 16 + quad * 4;
#pragma unroll
            for (int qs = 0; qs < 4; ++qs) {
                floatx4 acc = {0.f, 0.f, 0.f, 0.f};
                acc = MFMA16(a0.b, bq[qs][0].b, acc);
                acc = MFMA16(a1.b, bq[qs][1].b, acc);
                const int qg = qgroup * 64 + qs * 16 + n;
#pragma unroll
                for (int j = 0; j < 4; ++j) {
                    const float s = acc[j];
                    const int rowid = rowb + j;
                    if (s > th[qs] && (rowid >> 4) != qg) {
                        const int slot = atomicAdd(&cnt[qg], 1);
                        if (slot < CAP) ids[(size_t)qg * CAP + slot] = rowid;
                    }
                }
            }
            a0 = na0; a1 = na1;
        }
    }
}

// ---------------------------------------------------------------------------
// Kernel 4: final v3.1 (unchanged from R9 — wave-per-query, lane-0 broadcast).
// ---------------------------------------------------------------------------
__global__ __launch_bounds__(512) void final_kernel(
    const float* __restrict__ x,      // (N,T,F)
    const float* __restrict__ Qf,     // (2048,64)
    const float* __restrict__ Kmat,   // (32768,64)
    const int* __restrict__ cnt,
    const int* __restrict__ ids,
    const float* __restrict__ W1, const float* __restrict__ b1,
    const float* __restrict__ W2, const float* __restrict__ b2,
    float* __restrict__ out)          // (N,)
{
    const int t    = threadIdx.x;
    const int w    = t >> 6;
    const int lane = t & 63;
    const int grp  = lane >> 4;
    const int sl   = lane & 15;
    const int q    = blockIdx.x * 8 + w;

    const int mc0 = cnt[q];
    const int mc  = mc0 < CAP ? mc0 : CAP;
    const float4 qv = *(const float4*)(Qf + (size_t)q * 64 + sl * 4);
    const int* idq = ids + (size_t)q * CAP;

    float v[TOPKK]; int vid[TOPKK];
#pragma unroll
    for (int r = 0; r < TOPKK; ++r) { v[r] = -3e38f; vid[r] = -1; }
    float vmin = -3e38f; int imin = 0;

    for (int c = grp; c < mc; c += 4) {
        const int id = idq[c];
        const float4 kv = *(const float4*)(Kmat + (size_t)id * 64 + sl * 4);
        float p = qv.x * kv.x + qv.y * kv.y + qv.z * kv.z + qv.w * kv.w;
        p += __shfl_xor(p, 1, 64);
        p += __shfl_xor(p, 2, 64);
        p += __shfl_xor(p, 4, 64);
        p += __shfl_xor(p, 8, 64);
        if (sl == 0 && p > vmin) {
#pragma unroll
            for (int r = 0; r < TOPKK; ++r) if (r == imin) { v[r] = p; vid[r] = id; }
            vmin = v[0]; imin = 0;
#pragma unroll
            for (int r = 1; r < TOPKK; ++r) if (v[r] < vmin) { vmin = v[r]; imin = r; }
        }
    }

    float topv[TOPKK]; int topi[TOPKK];
    unsigned used = 0;
    for (int r = 0; r < TOPKK; ++r) {
        float bv = -3e38f; int bi = -1, bs = -1;
#pragma unroll
        for (int s = 0; s < TOPKK; ++s)
            if (!((used >> s) & 1) && v[s] > bv) { bv = v[s]; bi = vid[s]; bs = s; }
        const float mybv = bv; const int mybi = bi;
#pragma unroll
        for (int st = 16; st <= 32; st <<= 1) {
            const float ov = __shfl_xor(bv, st, 64);
            const int   oi = __shfl_xor(bi, st, 64);
            if (ov > bv || (ov == bv && oi > bi)) { bv = ov; bi = oi; }
        }
        topv[r] = bv; topi[r] = bi;
        if (bs >= 0 && mybv == bv && mybi == bi) used |= (1u << bs);
    }
#pragma unroll
    for (int r = 0; r < TOPKK; ++r) {
        topv[r] = __shfl(topv[r], 0, 64);
        topi[r] = __shfl(topi[r], 0, 64);
    }

    float mx = topv[0];
#pragma unroll
    for (int r = 1; r < TOPKK; ++r) mx = topv[r] > mx ? topv[r] : mx;
    float wgt[TOPKK]; float sw = 0.f;
#pragma unroll
    for (int r = 0; r < TOPKK; ++r) {
        wgt[r] = (topi[r] >= 0) ? __expf(topv[r] - mx) : 0.f;
        sw += wgt[r];
    }
    const float inv = 1.f / sw;

    float4 f0 = {0,0,0,0}, f1 = {0,0,0,0}, f2 = {0,0,0,0}, f3 = {0,0,0,0};
    if (lane < TOPKK && topi[lane] >= 0) {
        const int wi = topi[lane];
        const float* xr = x + ((size_t)(wi >> 4) * TT + 48 + (wi & 15)) * FF;
        const float s = wgt[lane] * inv;
        float4 a = *(const float4*)(xr);
        float4 b = *(const float4*)(xr + 4);
        float4 cc = *(const float4*)(xr + 8);
        float4 d = *(const float4*)(xr + 12);
        f0.x = s * a.x; f0.y = s * a.y; f0.z = s * a.z; f0.w = s * a.w;
        f1.x = s * b.x; f1.y = s * b.y; f1.z = s * b.z; f1.w = s * b.w;
        f2.x = s * cc.x; f2.y = s * cc.y; f2.z = s * cc.z; f2.w = s * cc.w;
        f3.x = s * d.x; f3.y = s * d.y; f3.z = s * d.z; f3.w = s * d.w;
    }
#pragma unroll
    for (int st = 1; st <= 8; st <<= 1) {
        f0.x += __shfl_xor(f0.x, st, 64); f0.y += __shfl_xor(f0.y, st, 64);
        f0.z += __shfl_xor(f0.z, st, 64); f0.w += __shfl_xor(f0.w, st, 64);
        f1.x += __shfl_xor(f1.x, st, 64); f1.y += __shfl_xor(f1.y, st, 64);
        f1.z += __shfl_xor(f1.z, st, 64); f1.w += __shfl_xor(f1.w, st, 64);
        f2.x += __shfl_xor(f2.x, st, 64); f2.y += __shfl_xor(f2.y, st, 64);
        f2.z += __shfl_xor(f2.z, st, 64); f2.w += __shfl_xor(f2.w, st, 64);
        f3.x += __shfl_xor(f3.x, st, 64); f3.y += __shfl_xor(f3.y, st, 64);
        f3.z += __shfl_xor(f3.z, st, 64); f3.w += __shfl_xor(f3.w, st, 64);
    }

    float o = 0.f;
    if (lane < 16) {
        const float* w1r = W1 + lane * 16;
        float hh = b1[lane]
            + f0.x * w1r[0]  + f0.y * w1r[1]  + f0.z * w1r[2]  + f0.w * w1r[3]
            + f1.x * w1r[4]  + f1.y * w1r[5]  + f1.z * w1r[6]  + f1.w * w1r[7]
            + f2.x * w1r[8]  + f2.y * w1r[9]  + f2.z * w1r[10] + f2.w * w1r[11]
            + f3.x * w1r[12] + f3.y * w1r[13] + f3.z * w1r[14] + f3.w * w1r[15];
        hh = hh > 0.f ? hh : 0.01f * hh;
        o = hh * W2[lane];
    }
#pragma unroll
    for (int st = 1; st <= 8; st <<= 1) o += __shfl_xor(o, st, 64);
    if (lane == 0) out[q] = o + b2[0];
}

// ---------------------------------------------------------------------------
extern "C" void kernel_launch(void* const* d_in, const int* in_sizes, int n_in,
                              void* d_out, int out_size, void* d_ws, size_t ws_size,
                              hipStream_t stream) {
    const float* x    = (const float*)d_in[0];
    const float* W_ih = (const float*)d_in[1];
    const float* W_hh = (const float*)d_in[2];
    const float* b_ih = (const float*)d_in[3];
    const float* b_hh = (const float*)d_in[4];
    const float* Wq   = (const float*)d_in[5];
    const float* Wk   = (const float*)d_in[6];
    const float* W1   = (const float*)d_in[7];
    const float* b1   = (const float*)d_in[8];
    const float* W2   = (const float*)d_in[9];
    const float* b2   = (const float*)d_in[10];
    float* outp = (float*)d_out;
    (void)ws_size; (void)n_in; (void)in_sizes; (void)out_size;

    float* h_tail        = (float*)d_ws;                                 // 8 MB
    int*   ids           = (int*)d_ws;                                   // overlay (after prep consumes h_tail)
    float* Kmat          = h_tail + (size_t)2048 * 1024;                 // 8 MB
    unsigned short* Kh   = (unsigned short*)(Kmat + (size_t)32768 * 64); // 4 MB
    float* Qf            = (float*)(Kh + (size_t)32768 * 64);            // 0.5 MB
    unsigned short* Qh   = (unsigned short*)(Qf + (size_t)2048 * 64);    // 0.25 MB
    int*   cnt           = (int*)(Qh + (size_t)2048 * 64);               // 8 KB

    gru_kernel<<<NN / 4, 256, 0, stream>>>(x, W_ih, W_hh, b_ih, b_hh, h_tail, cnt);
    prep_kernel<<<512, 256, 0, stream>>>(h_tail, Wk, Wq, Kmat, Kh, Qf, Qh);
    score_kernel<<<512, 512, 0, stream>>>(Kh, Qh, cnt, ids);
    final_kernel<<<NN / 8, 512, 0, stream>>>(x, Qf, Kmat, cnt, ids, W1, b1, W2, b2, outp);
}